// Round 1
// baseline (7192.535 us; speedup 1.0000x reference)
//
#include <hip/hip_runtime.h>

// Deep Kalman Filter inference, MI355X/gfx950.
// Phases: pack (weights -> fp16 MFMA-fragment order), rnn scan (16 WG),
// z scan (16 WG), parallel transition/emitter/loss (2048 WG), finalize.

#define T_LEN 512
#define BATCH 256
#define DIMX  128
#define ZDIM  128
#define TRD   256
#define EMD   256
#define RHD   512

typedef _Float16 f16;
typedef _Float16 f16x8 __attribute__((ext_vector_type(8)));
typedef float    f32x4 __attribute__((ext_vector_type(4)));

#define MFMA16(a,b,c) __builtin_amdgcn_mfma_f32_16x16x32_f16((a),(b),(c),0,0,0)

// ---- packed weight element offsets (f16 elements) ----
#define PK_WIH  0u
#define PK_WHH  65536u
#define PK_G1   327680u
#define PK_G2   360448u
#define PK_P1   393216u
#define PK_P2   425984u
#define PK_TMU  458752u
#define PK_TLV  475136u
#define PK_CBH  491520u
#define PK_CBML 557056u
#define PK_E1   688128u
#define PK_E2   720896u
#define PK_EMU  786432u
#define PK_TOTAL 819200u

// ---- workspace byte offsets ----
#define WS_RNN  0ull                          // f16 [T][B][RH]  134217728 B
#define WS_Z    (WS_RNN + 134217728ull)       // f16 [T+1][B][Z]  33619968 B
#define WS_MU   (WS_Z   + 33619968ull)        // f16 [T][B][Z]    33554432 B
#define WS_LV   (WS_MU  + 33554432ull)        // f16 [T][B][Z]    33554432 B
#define WS_PK   (WS_LV  + 33554432ull)        // f16 packed weights 1638400 B
#define WS_PART (WS_PK  + 1638400ull)         // f32 [2048][2]       16384 B
#define WS_END  (WS_PART + 16384ull)

// =====================================================================
// helpers
// =====================================================================
__device__ __forceinline__ void ldsfence() {
  asm volatile("s_waitcnt lgkmcnt(0)" ::: "memory");
  __builtin_amdgcn_sched_barrier(0);
}

template<int N>
__device__ __forceinline__ void zacc(f32x4* a) {
  f32x4 z = {0.f, 0.f, 0.f, 0.f};
#pragma unroll
  for (int i = 0; i < N; ++i) a[i] = z;
}

// A-operand fragment load from LDS tile [16][stride] (row = lane&15).
template<int KS>
__device__ __forceinline__ void load_af(const f16* src, int sstr, int lane, f16x8* af) {
#pragma unroll
  for (int ks = 0; ks < KS; ++ks)
    af[ks] = *(const f16x8*)(src + (lane & 15) * sstr + ks * 32 + ((lane >> 4) << 3));
}

// GEMM with A-frags in registers, B streamed from packed global memory.
// Packed layout: frag fi = ks*NT + nt, element = bp[fi*512 + lane*8 + j].
template<int KS, int NT>
__device__ __forceinline__ void gemm_regA(const f16x8* af, const f16* __restrict__ bp,
                                          int lane, f32x4* acc) {
#pragma unroll
  for (int ks = 0; ks < KS; ++ks)
#pragma unroll
    for (int j = 0; j < NT; ++j) {
      f16x8 bf = *(const f16x8*)(bp + (((size_t)(ks * NT + j)) << 9) + (lane << 3));
      acc[j] = MFMA16(af[ks], bf, acc[j]);
    }
}

// C-layout (row=(lane>>4)*4+r, col=lane&15) -> LDS fp16 with bias+relu
template<int NT>
__device__ __forceinline__ void store_relu(const f32x4* acc, const float* __restrict__ bias,
                                           f16* dst, int dstr, int lane) {
  int colv = lane & 15, rb = (lane >> 4) << 2;
#pragma unroll
  for (int j = 0; j < NT; ++j)
#pragma unroll
    for (int r = 0; r < 4; ++r)
      dst[(rb + r) * dstr + j * 16 + colv] = (f16)fmaxf(acc[j][r] + bias[j * 16 + colv], 0.f);
}

// =====================================================================
// pack: W[K][N] fp32 -> fp16 fragments for mfma_f32_16x16x32_f16 B-operand
// element (k,n): k = ks*32 + (l>>4)*8 + j, n = nt*16 + (l&15)
// dst[((ks*NT + nt)*64 + l)*8 + j]
// For the combined cb_mu|cb_lv matrix: n < nsplit -> s1, else s2.
// =====================================================================
__global__ void pack_kernel(const float* __restrict__ s1, const float* __restrict__ s2,
                            int nsplit, int K, int N, f16* __restrict__ dst) {
  int idx = blockIdx.x * 256 + threadIdx.x;
  if (idx >= K * N) return;
  int j = idx & 7, l = (idx >> 3) & 63, fi = idx >> 9;
  int NTt = N >> 4;
  int nt = fi % NTt, ks = fi / NTt;
  int k = ks * 32 + ((l >> 4) << 3) + j;
  int n = (nt << 4) + (l & 15);
  float v;
  if (n < nsplit) v = s1[(size_t)k * nsplit + n];
  else            v = s2[(size_t)k * (N - nsplit) + (n - nsplit)];
  dst[idx] = (f16)v;
}

// =====================================================================
// Phase B: RNN scan. 16 WGs x 512 threads; WG owns 16 batch rows.
// h = relu(x_t@Wih + h@Whh + bih + bhh). Wih in LDS, Whh streamed (L2).
// =====================================================================
__global__ __launch_bounds__(512) void rnn_kernel(
    const float* __restrict__ x, const f16* __restrict__ wih_p,
    const f16* __restrict__ whh_p, const float* __restrict__ bih,
    const float* __restrict__ bhh, const float* __restrict__ h0,
    f16* __restrict__ rnn_out) {
  __shared__ __align__(16) f16 wih_lds[65536];   // 128 KB
  __shared__ __align__(16) f16 h_lds[16 * 520];  // padded stride
  __shared__ __align__(16) f16 x_lds[16 * 136];
  const int tid = threadIdx.x, lane = tid & 63, w = tid >> 6;
  const int colv = lane & 15, rb = (lane >> 4) << 2;
  const int b0 = blockIdx.x * 16;

  for (int i = tid; i < 8192; i += 512)
    ((uint4*)wih_lds)[i] = ((const uint4*)wih_p)[i];
  for (int i = tid; i < 16 * 512; i += 512) {
    int r = i >> 9, n = i & 511;
    h_lds[r * 520 + n] = (f16)h0[n];
  }
  float bsum[4];
#pragma unroll
  for (int j = 0; j < 4; ++j) {
    int n = (w * 4 + j) * 16 + colv;
    bsum[j] = bih[n] + bhh[n];
  }
  __syncthreads();

  for (int t = 0; t < T_LEN; ++t) {
    for (int i = tid; i < 16 * DIMX; i += 512) {
      int r = i >> 7, d = i & 127;
      x_lds[r * 136 + d] = (f16)x[((size_t)(b0 + r) * T_LEN + t) * DIMX + d];
    }
    __syncthreads();
    f32x4 acc[4]; zacc<4>(acc);
    // x_t @ Wih  (K=128, LDS-resident B)
#pragma unroll
    for (int ks = 0; ks < 4; ++ks) {
      f16x8 a = *(const f16x8*)(x_lds + colv * 136 + ks * 32 + ((lane >> 4) << 3));
#pragma unroll
      for (int j = 0; j < 4; ++j) {
        f16x8 bf = *(const f16x8*)(wih_lds + ((ks * 32 + w * 4 + j) << 9) + (lane << 3));
        acc[j] = MFMA16(a, bf, acc[j]);
      }
    }
    // h @ Whh  (K=512, B streamed from L2)
#pragma unroll
    for (int ks = 0; ks < 16; ++ks) {
      f16x8 a = *(const f16x8*)(h_lds + colv * 520 + ks * 32 + ((lane >> 4) << 3));
#pragma unroll
      for (int j = 0; j < 4; ++j) {
        f16x8 bf = *(const f16x8*)(whh_p + (((size_t)(ks * 32 + w * 4 + j)) << 9) + (lane << 3));
        acc[j] = MFMA16(a, bf, acc[j]);
      }
    }
    __syncthreads();  // all waves done reading h_lds/x_lds
#pragma unroll
    for (int j = 0; j < 4; ++j)
#pragma unroll
      for (int r = 0; r < 4; ++r) {
        int row = rb + r, n = (w * 4 + j) * 16 + colv;
        f16 hv = (f16)fmaxf(acc[j][r] + bsum[j], 0.f);
        h_lds[row * 520 + n] = hv;
        rnn_out[((size_t)t * BATCH + b0 + row) * RHD + n] = hv;
      }
    __syncthreads();
  }
}

// =====================================================================
// Phase C: z scan. 16 WGs x 512 threads; WG owns 16 batch rows.
// hc = 0.5*(tanh(z@cbh + chb) + h_rnn); mu/lv = hc@[cbm|cbl]+b;
// z' = mu + eps*exp(0.5*lv). Stores z (f16), mu, lv (f16).
// =====================================================================
__global__ __launch_bounds__(512) void zscan_kernel(
    const f16* __restrict__ cbh_p, const f16* __restrict__ cbml_p,
    const float* __restrict__ chb, const float* __restrict__ cmb,
    const float* __restrict__ clb, const float* __restrict__ zq0,
    const f16* __restrict__ rnn_out, const float* __restrict__ eps_comb,
    f16* __restrict__ z_all, f16* __restrict__ mu_all, f16* __restrict__ lv_all) {
  __shared__ __align__(16) f16 cbh_lds[65536];   // 128 KB
  __shared__ __align__(16) f16 z_lds[16 * 136];
  __shared__ __align__(16) f16 hc_lds[16 * 520]; // also reused as mu/lv staging
  const int tid = threadIdx.x, lane = tid & 63, w = tid >> 6;
  const int colv = lane & 15, rb = (lane >> 4) << 2;
  const int b0 = blockIdx.x * 16;
  f16* mu_st = hc_lds;          // [16][128] overlay (after hc consumed)
  f16* lv_st = hc_lds + 2048;   // [16][128]

  for (int i = tid; i < 8192; i += 512)
    ((uint4*)cbh_lds)[i] = ((const uint4*)cbh_p)[i];
  for (int i = tid; i < 16 * 128; i += 512) {
    int r = i >> 7, zc = i & 127;
    f16 zv = (f16)zq0[zc];
    z_lds[r * 136 + zc] = zv;
    z_all[(size_t)(b0 + r) * ZDIM + zc] = zv;  // z_all[0]
  }
  float b1h[4];
#pragma unroll
  for (int j = 0; j < 4; ++j) b1h[j] = chb[(w * 4 + j) * 16 + colv];
  float b2h[2];
#pragma unroll
  for (int jj = 0; jj < 2; ++jj) {
    int n2 = (w * 2 + jj) * 16 + colv;
    b2h[jj] = (n2 < 128) ? cmb[n2] : clb[n2 - 128];
  }
  __syncthreads();

  for (int t = 0; t < T_LEN; ++t) {
    // GEMM1: z @ cbh (K=128, N=512, LDS-resident B)
    f32x4 acc[4]; zacc<4>(acc);
#pragma unroll
    for (int ks = 0; ks < 4; ++ks) {
      f16x8 a = *(const f16x8*)(z_lds + colv * 136 + ks * 32 + ((lane >> 4) << 3));
#pragma unroll
      for (int j = 0; j < 4; ++j) {
        f16x8 bf = *(const f16x8*)(cbh_lds + ((ks * 32 + w * 4 + j) << 9) + (lane << 3));
        acc[j] = MFMA16(a, bf, acc[j]);
      }
    }
#pragma unroll
    for (int j = 0; j < 4; ++j)
#pragma unroll
      for (int r = 0; r < 4; ++r) {
        int row = rb + r, n = (w * 4 + j) * 16 + colv;
        float hr = (float)rnn_out[((size_t)t * BATCH + b0 + row) * RHD + n];
        hc_lds[row * 520 + n] = (f16)(0.5f * (tanhf(acc[j][r] + b1h[j]) + hr));
      }
    __syncthreads();
    // GEMM2: hc @ [cbm|cbl] (K=512, N=256, B streamed)
    f32x4 a2[2]; zacc<2>(a2);
#pragma unroll
    for (int ks = 0; ks < 16; ++ks) {
      f16x8 a = *(const f16x8*)(hc_lds + colv * 520 + ks * 32 + ((lane >> 4) << 3));
#pragma unroll
      for (int jj = 0; jj < 2; ++jj) {
        f16x8 bf = *(const f16x8*)(cbml_p + (((size_t)(ks * 16 + w * 2 + jj)) << 9) + (lane << 3));
        a2[jj] = MFMA16(a, bf, a2[jj]);
      }
    }
    __syncthreads();  // hc consumed by all waves -> staging overlay safe
#pragma unroll
    for (int jj = 0; jj < 2; ++jj)
#pragma unroll
      for (int r = 0; r < 4; ++r) {
        int row = rb + r, n2 = (w * 2 + jj) * 16 + colv;
        float v = a2[jj][r] + b2h[jj];
        if (n2 < 128) mu_st[row * 128 + n2] = (f16)v;
        else          lv_st[row * 128 + (n2 - 128)] = (f16)v;
      }
    __syncthreads();
    // elementwise reparameterization + stores
    for (int i = tid; i < 2048; i += 512) {
      int r = i >> 7, zc = i & 127;
      float m_ = (float)mu_st[i], l_ = (float)lv_st[i];
      size_t o = ((size_t)t * BATCH + b0 + r) * ZDIM + zc;
      float zv = m_ + eps_comb[o] * expf(0.5f * l_);
      f16 zf = (f16)zv;
      z_lds[r * 136 + zc] = zf;
      z_all[o + (size_t)BATCH * ZDIM] = zf;  // slot t+1
      mu_all[o] = mu_st[i];
      lv_all[o] = lv_st[i];
    }
    __syncthreads();
  }
}

// =====================================================================
// Phase D: parallel transition/emitter/losses over all (t,b).
// 2048 WGs x 256 threads; each wave owns one 16-row tile (same t).
// =====================================================================
__global__ __launch_bounds__(256) void dpar_kernel(
    const f16* __restrict__ z_all, const f16* __restrict__ mu_all,
    const f16* __restrict__ lv_all, const float* __restrict__ y,
    const float* __restrict__ eps_emit, const f16* __restrict__ pk,
    const float* __restrict__ g1b, const float* __restrict__ g2b,
    const float* __restrict__ p1b, const float* __restrict__ p2b,
    const float* __restrict__ tmub, const float* __restrict__ tlvb,
    const float* __restrict__ e1b, const float* __restrict__ e2b,
    const float* __restrict__ emub, const float* __restrict__ em_logvar,
    float* __restrict__ partials) {
  __shared__ __align__(16) f16 sb256[4][16 * 264];
  __shared__ __align__(16) f16 sb128[4][16 * 136];
  __shared__ float wsum[4][2];
  const int tid = threadIdx.x, lane = tid & 63, w = tid >> 6;
  const int colv = lane & 15, rb = (lane >> 4) << 2;
  const int m0 = blockIdx.x * 64 + w * 16;
  const int t = m0 >> 8, b0 = m0 & 255;
  f16* B256 = &sb256[w][0];
  f16* B128 = &sb128[w][0];

  // z_prev / z_t fragment loads directly from global
  f16x8 zp[4], zt[4];
  const f16* zpr = z_all + ((size_t)t * BATCH + b0) * ZDIM;
#pragma unroll
  for (int ks = 0; ks < 4; ++ks) {
    zp[ks] = *(const f16x8*)(zpr + (size_t)colv * ZDIM + ks * 32 + ((lane >> 4) << 3));
    zt[ks] = *(const f16x8*)(zpr + (size_t)BATCH * ZDIM + (size_t)colv * ZDIM + ks * 32 + ((lane >> 4) << 3));
  }

  f32x4 a16[16], a8[8];
  f16x8 af[8], af4[4];
  // gate = sigmoid(relu(zp@g1+b)@g2+b)
  zacc<16>(a16); gemm_regA<4, 16>(zp, pk + PK_G1, lane, a16);
  store_relu<16>(a16, g1b, B256, 264, lane); ldsfence();
  load_af<8>(B256, 264, lane, af); ldsfence();
  zacc<8>(a8); gemm_regA<8, 8>(af, pk + PK_G2, lane, a8);
  f32x4 gate[8];
#pragma unroll
  for (int j = 0; j < 8; ++j)
#pragma unroll
    for (int r = 0; r < 4; ++r)
      gate[j][r] = 1.f / (1.f + expf(-(a8[j][r] + g2b[j * 16 + colv])));
  // prop = relu(zp@p1+b)@p2+b ; relu(prop) -> B128
  zacc<16>(a16); gemm_regA<4, 16>(zp, pk + PK_P1, lane, a16);
  store_relu<16>(a16, p1b, B256, 264, lane); ldsfence();
  load_af<8>(B256, 264, lane, af); ldsfence();
  zacc<8>(a8); gemm_regA<8, 8>(af, pk + PK_P2, lane, a8);
  f32x4 prop[8];
#pragma unroll
  for (int j = 0; j < 8; ++j)
#pragma unroll
    for (int r = 0; r < 4; ++r) {
      float v = a8[j][r] + p2b[j * 16 + colv];
      prop[j][r] = v;
      B128[(rb + r) * 136 + j * 16 + colv] = (f16)fmaxf(v, 0.f);
    }
  ldsfence();
  // pr_mu = (1-gate)*(zp@tmu+b) + gate*prop
  zacc<8>(a8); gemm_regA<4, 8>(zp, pk + PK_TMU, lane, a8);
  f32x4 prmu[8];
#pragma unroll
  for (int j = 0; j < 8; ++j)
#pragma unroll
    for (int r = 0; r < 4; ++r) {
      float g = gate[j][r];
      prmu[j][r] = (1.f - g) * (a8[j][r] + tmub[j * 16 + colv]) + g * prop[j][r];
    }
  // pr_lv = relu(prop)@tlv + b
  load_af<4>(B128, 136, lane, af4); ldsfence();
  zacc<8>(a8); gemm_regA<4, 8>(af4, pk + PK_TLV, lane, a8);
  f32x4 prlv[8];
#pragma unroll
  for (int j = 0; j < 8; ++j)
#pragma unroll
    for (int r = 0; r < 4; ++r) prlv[j][r] = a8[j][r] + tlvb[j * 16 + colv];
  // emitter: x_mu = relu(relu(zt@e1+b)@e2+b)@emu + b
  zacc<16>(a16); gemm_regA<4, 16>(zt, pk + PK_E1, lane, a16);
  store_relu<16>(a16, e1b, B256, 264, lane); ldsfence();
  load_af<8>(B256, 264, lane, af); ldsfence();
  zacc<16>(a16); gemm_regA<8, 16>(af, pk + PK_E2, lane, a16);
  store_relu<16>(a16, e2b, B256, 264, lane); ldsfence();
  load_af<8>(B256, 264, lane, af); ldsfence();
  zacc<8>(a8); gemm_regA<8, 8>(af, pk + PK_EMU, lane, a8);
  // losses
  float srec = 0.f, skl = 0.f;
#pragma unroll
  for (int j = 0; j < 8; ++j)
#pragma unroll
    for (int r = 0; r < 4; ++r) {
      int row = rb + r, n = j * 16 + colv;
      size_t tb = (size_t)t * BATCH + b0 + row;
      float xt = a8[j][r] + emub[n] + eps_emit[tb * DIMX + n] * expf(0.5f * em_logvar[n]);
      float dy = xt - y[((size_t)(b0 + row) * T_LEN + t) * DIMX + n];
      srec += dy * dy;
      float m_ = (float)mu_all[tb * ZDIM + n], l_ = (float)lv_all[tb * ZDIM + n];
      float dm = m_ - prmu[j][r];
      skl += 0.5f * (prlv[j][r] - l_ + (expf(l_) + dm * dm) * expf(-prlv[j][r]) - 1.f);
    }
#pragma unroll
  for (int off = 32; off; off >>= 1) {
    srec += __shfl_xor(srec, off);
    skl += __shfl_xor(skl, off);
  }
  if (lane == 0) { wsum[w][0] = srec; wsum[w][1] = skl; }
  __syncthreads();
  if (tid == 0) {
    partials[blockIdx.x * 2 + 0] = wsum[0][0] + wsum[1][0] + wsum[2][0] + wsum[3][0];
    partials[blockIdx.x * 2 + 1] = wsum[0][1] + wsum[1][1] + wsum[2][1] + wsum[3][1];
  }
}

// =====================================================================
// finalize: deterministic fixed-order reduction of 2048 partials
// =====================================================================
__global__ void finalize_kernel(const float* __restrict__ partials, float* __restrict__ out) {
  __shared__ float s[256][2];
  int tid = threadIdx.x;
  float r = 0.f, k = 0.f;
  for (int i = tid; i < 2048; i += 256) {
    r += partials[2 * i];
    k += partials[2 * i + 1];
  }
  s[tid][0] = r; s[tid][1] = k;
  __syncthreads();
  for (int off = 128; off; off >>= 1) {
    if (tid < off) { s[tid][0] += s[tid + off][0]; s[tid][1] += s[tid + off][1]; }
    __syncthreads();
  }
  if (tid == 0) {
    out[0] = s[0][0] / (131072.f * 128.f);  // mean over (T,B,D)
    out[1] = s[0][1] / 131072.f;            // mean over (T,B)
  }
}

// =====================================================================
extern "C" void kernel_launch(void* const* d_in, const int* in_sizes, int n_in,
                              void* d_out, int out_size, void* d_ws, size_t ws_size,
                              hipStream_t stream) {
  (void)in_sizes; (void)n_in; (void)out_size;
  const float* x        = (const float*)d_in[0];
  const float* y        = (const float*)d_in[1];
  const float* eps_comb = (const float*)d_in[2];
  const float* eps_emit = (const float*)d_in[3];
  const float* wih = (const float*)d_in[4];
  const float* whh = (const float*)d_in[5];
  const float* bih = (const float*)d_in[6];
  const float* bhh = (const float*)d_in[7];
  const float* h0  = (const float*)d_in[8];
  const float* zq0 = (const float*)d_in[9];
  const float* g1W = (const float*)d_in[10]; const float* g1b = (const float*)d_in[11];
  const float* g2W = (const float*)d_in[12]; const float* g2b = (const float*)d_in[13];
  const float* p1W = (const float*)d_in[14]; const float* p1b = (const float*)d_in[15];
  const float* p2W = (const float*)d_in[16]; const float* p2b = (const float*)d_in[17];
  const float* tmuW = (const float*)d_in[18]; const float* tmub = (const float*)d_in[19];
  const float* tlvW = (const float*)d_in[20]; const float* tlvb = (const float*)d_in[21];
  const float* chW = (const float*)d_in[22]; const float* chb = (const float*)d_in[23];
  const float* cmW = (const float*)d_in[24]; const float* cmb = (const float*)d_in[25];
  const float* clW = (const float*)d_in[26]; const float* clb = (const float*)d_in[27];
  const float* e1W = (const float*)d_in[28]; const float* e1b = (const float*)d_in[29];
  const float* e2W = (const float*)d_in[30]; const float* e2b = (const float*)d_in[31];
  const float* emW = (const float*)d_in[32]; const float* emb = (const float*)d_in[33];
  const float* elv = (const float*)d_in[34];

  char* ws = (char*)d_ws;
  f16*  rnn_out = (f16*)(ws + WS_RNN);
  f16*  z_all   = (f16*)(ws + WS_Z);
  f16*  mu_all  = (f16*)(ws + WS_MU);
  f16*  lv_all  = (f16*)(ws + WS_LV);
  f16*  pk      = (f16*)(ws + WS_PK);
  float* partials = (float*)(ws + WS_PART);
  float* out = (float*)d_out;
  if (ws_size < WS_END) return;  // workspace too small; cannot proceed safely

#define PACK(S1, S2, NS, K, N, OFF) \
  pack_kernel<<<dim3(((K) * (N)) / 256), dim3(256), 0, stream>>>(S1, S2, NS, K, N, pk + (OFF))
  PACK(wih, wih, 512, 128, 512, PK_WIH);
  PACK(whh, whh, 512, 512, 512, PK_WHH);
  PACK(g1W, g1W, 256, 128, 256, PK_G1);
  PACK(g2W, g2W, 128, 256, 128, PK_G2);
  PACK(p1W, p1W, 256, 128, 256, PK_P1);
  PACK(p2W, p2W, 128, 256, 128, PK_P2);
  PACK(tmuW, tmuW, 128, 128, 128, PK_TMU);
  PACK(tlvW, tlvW, 128, 128, 128, PK_TLV);
  PACK(chW, chW, 512, 128, 512, PK_CBH);
  PACK(cmW, clW, 128, 512, 256, PK_CBML);
  PACK(e1W, e1W, 256, 128, 256, PK_E1);
  PACK(e2W, e2W, 256, 256, 256, PK_E2);
  PACK(emW, emW, 128, 256, 128, PK_EMU);
#undef PACK

  rnn_kernel<<<dim3(16), dim3(512), 0, stream>>>(x, pk + PK_WIH, pk + PK_WHH, bih, bhh, h0, rnn_out);
  zscan_kernel<<<dim3(16), dim3(512), 0, stream>>>(pk + PK_CBH, pk + PK_CBML, chb, cmb, clb, zq0,
                                                   rnn_out, eps_comb, z_all, mu_all, lv_all);
  dpar_kernel<<<dim3(2048), dim3(256), 0, stream>>>(z_all, mu_all, lv_all, y, eps_emit, pk,
                                                    g1b, g2b, p1b, p2b, tmub, tlvb, e1b, e2b,
                                                    emb, elv, partials);
  finalize_kernel<<<dim3(1), dim3(256), 0, stream>>>(partials, out);
}